// Round 1
// baseline (778.676 us; speedup 1.0000x reference)
//
#include <hip/hip_runtime.h>
#include <cmath>

// Problem constants (B=1, C=128, D=H=W=24)
#define LSEQ 13824   // 24*24*24
#define NCH  216     // chunks per direction
#define TC   64      // chunk length (NCH*TC == LSEQ)

__device__ __forceinline__ int can_of_l(int mode, int l) {
  // canonical flat (d*576 + h*24 + w) index of sequence position l
  if (mode == 0) return l;
  int a = l / 576;
  int r = l - a * 576;
  int b = r / 24;
  int e = r - b * 24;
  // mode1: l = h*576 + w*24 + d -> (a,b,e)=(h,w,d) -> can = d*576+h*24+w
  // mode2: l = w*576 + d*24 + h -> (a,b,e)=(w,d,h) -> can = d*576+h*24+w
  return (mode == 1) ? (e * 576 + a * 24 + b) : (b * 576 + e * 24 + a);
}

__device__ __forceinline__ int l_of_can(int mode, int can) {
  if (mode == 0) return can;
  int d = can / 576;
  int r = can - d * 576;
  int h = r / 24;
  int w = r - h * 24;
  return (mode == 1) ? (h * 576 + w * 24 + d) : (w * 576 + d * 24 + h);
}

__device__ __forceinline__ float softplusf(float x) {
  return x > 20.f ? x : log1pf(__expf(x));
}
__device__ __forceinline__ float siluf(float x) {
  return x / (1.f + __expf(-x));
}

// ---------------------------------------------------------------------------
// K1: LayerNorm + in_proj + causal depthwise conv + silu + xproj + local scan
// grid: 2*NCH blocks (dir = bid&1, chunk = bid>>1), 256 threads
// ---------------------------------------------------------------------------
__global__ __launch_bounds__(256, 2) void k_front(
    int mode,
    const float* __restrict__ cur,
    const float* __restrict__ inw,
    const float* __restrict__ cw,
    const float* __restrict__ cbv,
    const float* __restrict__ xpw,
    const float* __restrict__ dpw,
    const float* __restrict__ dpb,
    const float* __restrict__ alog,
    const float* __restrict__ lng,
    const float* __restrict__ lnb,
    float* __restrict__ xc_g,
    float* __restrict__ z_g,
    float* __restrict__ bc_g,
    float* __restrict__ P_g,
    float* __restrict__ S_g)
{
  __shared__ float u_s[35 * 64];     // LN output (one 64-ch half), 32+3 halo rows
  __shared__ float xc0_s[35 * 128];  // pre-conv in_proj output
  __shared__ float dbc_s[TC * 20];   // xproj output for whole chunk

  const int tid   = threadIdx.x;
  const int dirv  = blockIdx.x & 1;
  const int chunk = blockIdx.x >> 1;
  const int c0    = chunk * TC;
  const int jb    = mode * 2 + dirv;

  // preload this thread's in_proj row (e = tid, 64 weights)
  float wreg[64];
  {
    const float4* wp = (const float4*)(inw + ((size_t)jb * 256 + tid) * 64);
#pragma unroll
    for (int k = 0; k < 16; ++k) {
      float4 t = wp[k];
      wreg[4 * k + 0] = t.x; wreg[4 * k + 1] = t.y;
      wreg[4 * k + 2] = t.z; wreg[4 * k + 3] = t.w;
    }
  }
  // conv params for phase C
  const int dC = tid & 127;
  float cwr[4];
#pragma unroll
  for (int k = 0; k < 4; ++k) cwr[k] = cw[(size_t)jb * 512 + dC * 4 + k];
  const float cbr = cbv[(size_t)jb * 128 + dC];

  const int wv   = tid >> 6;
  const int lane = tid & 63;
  const int pg   = lane >> 3;  // position within wave-iter (8 pos/wave)
  const int g    = lane & 7;   // channel group (16 ch each)

  for (int st = 0; st < 2; ++st) {
    if (st) __syncthreads();
    const int p0 = c0 + st * 32 - 3;  // first (halo) row's sequence position

    // ---- Phase A: LayerNorm -> u (35 rows) ----
#pragma unroll
    for (int it = 0; it < 2; ++it) {
      int tp = it * 32 + wv * 8 + pg;
      if (tp < 35) {
        int p = p0 + tp;
        int rel = g * 16 - dirv * 64;   // offset of this lane's channels in dir half
        if (p >= 0) {
          int l = dirv ? (LSEQ - 1 - p) : p;
          int can = can_of_l(mode, l);
          const float* src = cur + (size_t)(g * 16) * LSEQ + can;
          float v[16];
#pragma unroll
          for (int i = 0; i < 16; ++i) v[i] = src[(size_t)i * LSEQ];
          float s = 0.f, s2 = 0.f;
#pragma unroll
          for (int i = 0; i < 16; ++i) { s += v[i]; s2 += v[i] * v[i]; }
#pragma unroll
          for (int mk = 1; mk < 8; mk <<= 1) {
            s  += __shfl_xor(s,  mk, 64);
            s2 += __shfl_xor(s2, mk, 64);
          }
          if (rel >= 0 && rel < 64) {
            float mean = s * (1.f / 128.f);
            float var  = s2 * (1.f / 128.f) - mean * mean;
            float rstd = rsqrtf(var + 1e-5f);
#pragma unroll
            for (int i = 0; i < 16; ++i) {
              int ch = g * 16 + i;
              u_s[tp * 64 + rel + i] =
                  (v[i] - mean) * rstd * lng[mode * 128 + ch] + lnb[mode * 128 + ch];
            }
          }
        } else {
          // causal zero padding: u=0 -> xc0=0 (conv pad)
          if (rel >= 0 && rel < 64) {
#pragma unroll
            for (int i = 0; i < 16; ++i) u_s[tp * 64 + rel + i] = 0.f;
          }
        }
      }
    }
    __syncthreads();

    // ---- Phase B: in_proj (e = tid; e<128 -> xc0, e>=128 -> z) ----
    for (int tp = 0; tp < 35; ++tp) {
      const float* up = u_s + tp * 64;
      float a0 = 0.f, a1 = 0.f, a2 = 0.f, a3 = 0.f;
#pragma unroll
      for (int k = 0; k < 64; k += 4) {
        a0 += up[k + 0] * wreg[k + 0];
        a1 += up[k + 1] * wreg[k + 1];
        a2 += up[k + 2] * wreg[k + 2];
        a3 += up[k + 3] * wreg[k + 3];
      }
      float acc = (a0 + a1) + (a2 + a3);
      if (tid < 128) {
        xc0_s[tp * 128 + tid] = acc;
      } else if (tp >= 3) {
        z_g[((size_t)dirv * LSEQ + (p0 + tp)) * 128 + (tid - 128)] = acc;
      }
    }
    __syncthreads();

    // ---- Phase C: depthwise causal conv(4) + bias + silu -> xc_g ----
    {
      const int mh = tid >> 7;
      for (int m = mh; m < 32; m += 2) {
        float s = cbr;
#pragma unroll
        for (int k = 0; k < 4; ++k) s += cwr[k] * xc0_s[(m + k) * 128 + dC];
        xc_g[((size_t)dirv * LSEQ + (c0 + st * 32 + m)) * 128 + dC] = siluf(s);
      }
    }
  }
  __syncthreads();

  // ---- Phase D: xproj (20 outputs per position) ----
  for (int it = 0; it < 8; ++it) {
    int idx = tid + 256 * it;
    int mp = idx >> 5, e = idx & 31;
    if (e < 20) {
      const float* xr = xc_g + ((size_t)dirv * LSEQ + (c0 + mp)) * 128;
      const float* wr = xpw + ((size_t)jb * 20 + e) * 128;
      float a0 = 0.f, a1 = 0.f, a2 = 0.f, a3 = 0.f;
#pragma unroll
      for (int k = 0; k < 128; k += 4) {
        a0 += xr[k + 0] * wr[k + 0];
        a1 += xr[k + 1] * wr[k + 1];
        a2 += xr[k + 2] * wr[k + 2];
        a3 += xr[k + 3] * wr[k + 3];
      }
      float acc = (a0 + a1) + (a2 + a3);
      dbc_s[mp * 20 + e] = acc;
      bc_g[((size_t)dirv * LSEQ + (c0 + mp)) * 20 + e] = acc;
    }
  }
  __syncthreads();

  // ---- Phase F: local chunk scan -> P (prod of dA), S (state from zero) ----
  {
    const int dd = tid >> 1;
    const int sb = (tid & 1) * 4;
    float Ar[4], dpwr[4];
#pragma unroll
    for (int j = 0; j < 4; ++j) Ar[j] = -__expf(alog[(size_t)jb * 1024 + dd * 8 + sb + j]);
#pragma unroll
    for (int r = 0; r < 4; ++r) dpwr[r] = dpw[(size_t)jb * 512 + dd * 4 + r];
    const float dpbr = dpb[(size_t)jb * 128 + dd];
    float hP[4] = {1.f, 1.f, 1.f, 1.f};
    float hS[4] = {0.f, 0.f, 0.f, 0.f};
    float xcv_n = xc_g[((size_t)dirv * LSEQ + c0) * 128 + dd];
    for (int mp = 0; mp < TC; ++mp) {
      float xcv = xcv_n;
      if (mp + 1 < TC) xcv_n = xc_g[((size_t)dirv * LSEQ + (c0 + mp + 1)) * 128 + dd];
      float dtacc = dpbr;
#pragma unroll
      for (int r = 0; r < 4; ++r) dtacc += dbc_s[mp * 20 + r] * dpwr[r];
      float dtv = softplusf(dtacc);
      float du = dtv * xcv;
#pragma unroll
      for (int j = 0; j < 4; ++j) {
        float dA = __expf(dtv * Ar[j]);
        hP[j] *= dA;
        hS[j] = dA * hS[j] + du * dbc_s[mp * 20 + 4 + sb + j];
      }
    }
    size_t o = ((size_t)dirv * NCH + chunk) * 1024 + (size_t)tid * 4;
    P_g[o + 0] = hP[0]; P_g[o + 1] = hP[1]; P_g[o + 2] = hP[2]; P_g[o + 3] = hP[3];
    S_g[o + 0] = hS[0]; S_g[o + 1] = hS[1]; S_g[o + 2] = hS[2]; S_g[o + 3] = hS[3];
  }
}

// ---------------------------------------------------------------------------
// K2: scan over chunk summaries -> prefix state per chunk
// ---------------------------------------------------------------------------
__global__ void k_cscan(const float* __restrict__ P_g, const float* __restrict__ S_g,
                        float* __restrict__ pref_g)
{
  int gid = blockIdx.x * 256 + threadIdx.x;  // 2048 threads = 2 dirs * 1024 states
  int dir = gid >> 10, q = gid & 1023;
  float h = 0.f;
  for (int c = 0; c < NCH; ++c) {
    size_t o = ((size_t)dir * NCH + c) * 1024 + q;
    pref_g[o] = h;
    h = P_g[o] * h + S_g[o];
  }
}

// ---------------------------------------------------------------------------
// K3: re-scan with prefix, y = hC + D*xc, *= silu(z), outproj -> ofb
// grid: 2*NCH blocks, 256 threads
// ---------------------------------------------------------------------------
__global__ __launch_bounds__(256, 2) void k_back(
    int mode,
    const float* __restrict__ xc_g,
    const float* __restrict__ z_g,
    const float* __restrict__ bc_g,
    const float* __restrict__ pref_g,
    const float* __restrict__ dpw,
    const float* __restrict__ dpb,
    const float* __restrict__ alog,
    const float* __restrict__ dpar,
    const float* __restrict__ opw,
    float* __restrict__ ofb)
{
  __shared__ float opwT[128 * 65];  // opw transposed [d][o], padded
  __shared__ float y_s[128 * 34];   // y tile [d][pos(32)], padded
  __shared__ float bc_s[TC * 20];

  const int tid   = threadIdx.x;
  const int dirv  = blockIdx.x & 1;
  const int chunk = blockIdx.x >> 1;
  const int c0    = chunk * TC;
  const int jb    = mode * 2 + dirv;

  for (int idx = tid; idx < 128 * 64; idx += 256) {
    int ddl = idx & 127, o = idx >> 7;
    opwT[ddl * 65 + o] = opw[((size_t)jb * 64 + o) * 128 + ddl];
  }
  for (int idx = tid; idx < TC * 20; idx += 256)
    bc_s[idx] = bc_g[((size_t)dirv * LSEQ + c0) * 20 + idx];

  const int dd = tid >> 1;
  const int sb = (tid & 1) * 4;
  float Ar[4], dpwr[4];
#pragma unroll
  for (int j = 0; j < 4; ++j) Ar[j] = -__expf(alog[(size_t)jb * 1024 + dd * 8 + sb + j]);
#pragma unroll
  for (int r = 0; r < 4; ++r) dpwr[r] = dpw[(size_t)jb * 512 + dd * 4 + r];
  const float dpbr = dpb[(size_t)jb * 128 + dd];
  const float Dp = dpar[(size_t)jb * 128 + dd];
  float h[4];
  {
    size_t o = ((size_t)dirv * NCH + chunk) * 1024 + (size_t)tid * 4;
    h[0] = pref_g[o + 0]; h[1] = pref_g[o + 1];
    h[2] = pref_g[o + 2]; h[3] = pref_g[o + 3];
  }
  __syncthreads();

  for (int q = 0; q < 2; ++q) {
    if (q) __syncthreads();
    // ---- scan 32 steps, produce y tile ----
    float xcv_n = xc_g[((size_t)dirv * LSEQ + (c0 + q * 32)) * 128 + dd];
    for (int m2 = 0; m2 < 32; ++m2) {
      int mp = q * 32 + m2;
      float xcv = xcv_n;
      if (m2 < 31) xcv_n = xc_g[((size_t)dirv * LSEQ + (c0 + mp + 1)) * 128 + dd];
      float dtacc = dpbr;
#pragma unroll
      for (int r = 0; r < 4; ++r) dtacc += bc_s[mp * 20 + r] * dpwr[r];
      float dtv = softplusf(dtacc);
      float du = dtv * xcv;
      float ysum = 0.f;
#pragma unroll
      for (int j = 0; j < 4; ++j) {
        float dA = __expf(dtv * Ar[j]);
        h[j] = dA * h[j] + du * bc_s[mp * 20 + 4 + sb + j];
        ysum += h[j] * bc_s[mp * 20 + 12 + sb + j];
      }
      ysum += __shfl_xor(ysum, 1, 64);
      if ((tid & 1) == 0) {
        float zv = z_g[((size_t)dirv * LSEQ + (c0 + mp)) * 128 + dd];
        y_s[dd * 34 + m2] = (ysum + Dp * xcv) * siluf(zv);
      }
    }
    __syncthreads();
    // ---- outproj for these 32 positions ----
    {
      const int o  = tid & 63;
      const int pb = (tid >> 6) * 8;
      float acc[8] = {0.f, 0.f, 0.f, 0.f, 0.f, 0.f, 0.f, 0.f};
      for (int k = 0; k < 128; ++k) {
        float wvv = opwT[k * 65 + o];
        const float2* yp = (const float2*)(y_s + k * 34 + pb);
#pragma unroll
        for (int i2 = 0; i2 < 4; ++i2) {
          float2 yv = yp[i2];
          acc[2 * i2]     += yv.x * wvv;
          acc[2 * i2 + 1] += yv.y * wvv;
        }
      }
#pragma unroll
      for (int i = 0; i < 8; ++i) {
        int p = c0 + q * 32 + pb + i;
        int lo = dirv ? (LSEQ - 1 - p) : p;
        ofb[((size_t)dirv * LSEQ + lo) * 64 + o] = acc[i];
      }
    }
  }
}

// ---------------------------------------------------------------------------
// K4: combine fwd/bwd + residual (+ x on final mode), canonical layout write
// grid: dim3(54, 128), 256 threads
// ---------------------------------------------------------------------------
__global__ void k_comb(
    int mode,
    const float* __restrict__ cur_in,
    const float* __restrict__ ofb,
    const float* __restrict__ x_in,
    float* __restrict__ cur_out,
    int add_x)
{
  int can = blockIdx.x * 256 + threadIdx.x;  // 54*256 == 13824
  int c2 = blockIdx.y;                       // channel 0..127
  int l = l_of_can(mode, can);
  int dirv = c2 >> 6, o = c2 & 63;
  size_t ci = (size_t)c2 * LSEQ + can;
  float v = ofb[((size_t)dirv * LSEQ + l) * 64 + o] + cur_in[ci];
  if (add_x) v += x_in[ci];
  cur_out[ci] = v;
}

// ---------------------------------------------------------------------------
extern "C" void kernel_launch(void* const* d_in, const int* in_sizes, int n_in,
                              void* d_out, int out_size, void* d_ws, size_t ws_size,
                              hipStream_t stream)
{
  const float* x    = (const float*)d_in[0];
  const float* inw  = (const float*)d_in[1];
  const float* cw   = (const float*)d_in[2];
  const float* cb   = (const float*)d_in[3];
  const float* xpw  = (const float*)d_in[4];
  const float* dpw  = (const float*)d_in[5];
  const float* dpb  = (const float*)d_in[6];
  const float* alog = (const float*)d_in[7];
  const float* dpar = (const float*)d_in[8];
  const float* opw  = (const float*)d_in[9];
  const float* lng  = (const float*)d_in[10];
  const float* lnb  = (const float*)d_in[11];
  float* out = (float*)d_out;

  // workspace layout (fp32), total ~57.1 MB
  float* ws = (float*)d_ws;
  const size_t LC = (size_t)LSEQ * 128;
  float* curA = ws;
  float* curB = curA + LC;
  float* xc_g = curB + LC;                       // 2*LC
  float* z_g  = xc_g + 2 * LC;                   // 2*LC
  float* bc_g = z_g + 2 * LC;                    // 2*LSEQ*20
  float* P_g  = bc_g + 2 * (size_t)LSEQ * 20;    // 2*NCH*1024
  float* S_g  = P_g + 2 * (size_t)NCH * 1024;
  float* pref = S_g + 2 * (size_t)NCH * 1024;
  float* ofb  = pref + 2 * (size_t)NCH * 1024;   // 2*LSEQ*64

  for (int m = 0; m < 3; ++m) {
    const float* cin = (m == 0) ? x : ((m == 1) ? curA : curB);
    float* cout = (m == 0) ? curA : ((m == 1) ? curB : out);
    k_front<<<dim3(2 * NCH), dim3(256), 0, stream>>>(
        m, cin, inw, cw, cb, xpw, dpw, dpb, alog, lng, lnb,
        xc_g, z_g, bc_g, P_g, S_g);
    k_cscan<<<dim3(8), dim3(256), 0, stream>>>(P_g, S_g, pref);
    k_back<<<dim3(2 * NCH), dim3(256), 0, stream>>>(
        m, xc_g, z_g, bc_g, pref, dpw, dpb, alog, dpar, opw, ofb);
    k_comb<<<dim3(54, 128), dim3(256), 0, stream>>>(
        m, cin, ofb, x, cout, (m == 2) ? 1 : 0);
  }
}